// Round 4
// baseline (114.894 us; speedup 1.0000x reference)
//
#include <hip/hip_runtime.h>
#include <hip/hip_bf16.h>

// Fused: out[b,o,h,w] = clip( sum_c x[b,c,h,w] * w2d[o,c] * styles[b,c] + bias[o], -256, 256 )
// styles[b,c] = (dot(w[b,:], affine_w[c,:]) / sqrt(512) + affine_b[c]) / sqrt(256)
// B=8, C_in=256, H=W=256, C_out=3, w_dim=512.  All fp32.
//
// Single kernel: each block computes the 256 modulated weights for its batch b
// in a prologue (thread t owns channel c=t; w[b,:] is block-uniform -> scalar
// loads; affine_w re-reads hit L2/L3, ~0.5 MB HBM once), then streams x.

#define B_    8
#define CIN   256
#define HW    65536          // 256*256
#define HW4   16384          // HW/4
#define COUT  3
#define WDIM  512

typedef float f4 __attribute__((ext_vector_type(4)));

__global__ __launch_bounds__(256) void fused_modconv_kernel(
    const float* __restrict__ x,          // (B, 256, 256, 256)
    const float* __restrict__ w,          // (B, 512)
    const float* __restrict__ weight,     // (3, 256)
    const float* __restrict__ bias,       // (3,)
    const float* __restrict__ affine_w,   // (256, 512)
    const float* __restrict__ affine_b,   // (256,)
    float* __restrict__ out)              // (B, 3, 256, 256)
{
    const int b    = blockIdx.y;
    const int tile = blockIdx.x;        // 64 tiles of 1024 floats each
    const int tid  = threadIdx.x;       // 256; also the channel this thread modulates

    __shared__ f4 ms[CIN];

    // ---- Prologue: styles[b, tid] and modulated weights -> LDS ----
    {
        const f4* aw = (const f4*)(affine_w + (size_t)tid * WDIM);
        const f4* wv = (const f4*)(w + (size_t)b * WDIM);   // block-uniform
        f4 acc4 = {0.f, 0.f, 0.f, 0.f};
#pragma unroll 8
        for (int i = 0; i < WDIM / 4; ++i) {
            f4 a = aw[i];
            f4 q = wv[i];
            acc4.x = fmaf(a.x, q.x, acc4.x);
            acc4.y = fmaf(a.y, q.y, acc4.y);
            acc4.z = fmaf(a.z, q.z, acc4.z);
            acc4.w = fmaf(a.w, q.w, acc4.w);
        }
        float acc = (acc4.x + acc4.y) + (acc4.z + acc4.w);
        const float rs512 = 0.044194173824159216f;  // 1/sqrt(512)
        const float rs256 = 0.0625f;                // 1/sqrt(256)
        float s = (acc * rs512 + affine_b[tid]) * rs256;
        f4 m;
        m.x = weight[0 * CIN + tid] * s;
        m.y = weight[1 * CIN + tid] * s;
        m.z = weight[2 * CIN + tid] * s;
        m.w = 0.f;
        ms[tid] = m;
    }
    __syncthreads();

    // ---- Main loop: stream x, accumulate 3 output channels ----
    const f4* xp = (const f4*)x + (size_t)b * CIN * HW4 + (size_t)tile * 256 + tid;

    const float b0 = bias[0], b1 = bias[1], b2 = bias[2];
    f4 a0 = {b0, b0, b0, b0};
    f4 a1 = {b1, b1, b1, b1};
    f4 a2 = {b2, b2, b2, b2};

#pragma unroll 16
    for (int c = 0; c < CIN; ++c) {
        f4 xv = __builtin_nontemporal_load(xp + (size_t)c * HW4);
        f4 m  = ms[c];
        a0.x = fmaf(xv.x, m.x, a0.x);
        a0.y = fmaf(xv.y, m.x, a0.y);
        a0.z = fmaf(xv.z, m.x, a0.z);
        a0.w = fmaf(xv.w, m.x, a0.w);
        a1.x = fmaf(xv.x, m.y, a1.x);
        a1.y = fmaf(xv.y, m.y, a1.y);
        a1.z = fmaf(xv.z, m.y, a1.z);
        a1.w = fmaf(xv.w, m.y, a1.w);
        a2.x = fmaf(xv.x, m.z, a2.x);
        a2.y = fmaf(xv.y, m.z, a2.y);
        a2.z = fmaf(xv.z, m.z, a2.z);
        a2.w = fmaf(xv.w, m.z, a2.w);
    }

    const float CL = 256.0f;
    a0.x = fminf(fmaxf(a0.x, -CL), CL);
    a0.y = fminf(fmaxf(a0.y, -CL), CL);
    a0.z = fminf(fmaxf(a0.z, -CL), CL);
    a0.w = fminf(fmaxf(a0.w, -CL), CL);
    a1.x = fminf(fmaxf(a1.x, -CL), CL);
    a1.y = fminf(fmaxf(a1.y, -CL), CL);
    a1.z = fminf(fmaxf(a1.z, -CL), CL);
    a1.w = fminf(fmaxf(a1.w, -CL), CL);
    a2.x = fminf(fmaxf(a2.x, -CL), CL);
    a2.y = fminf(fmaxf(a2.y, -CL), CL);
    a2.z = fminf(fmaxf(a2.z, -CL), CL);
    a2.w = fminf(fmaxf(a2.w, -CL), CL);

    f4* op = (f4*)out + (size_t)b * COUT * HW4 + (size_t)tile * 256 + tid;
    __builtin_nontemporal_store(a0, op + 0 * HW4);
    __builtin_nontemporal_store(a1, op + 1 * HW4);
    __builtin_nontemporal_store(a2, op + 2 * HW4);
}

extern "C" void kernel_launch(void* const* d_in, const int* in_sizes, int n_in,
                              void* d_out, int out_size, void* d_ws, size_t ws_size,
                              hipStream_t stream) {
    const float* x        = (const float*)d_in[0];
    const float* w        = (const float*)d_in[1];
    const float* weight   = (const float*)d_in[2];
    const float* bias     = (const float*)d_in[3];
    const float* affine_w = (const float*)d_in[4];
    const float* affine_b = (const float*)d_in[5];
    float* out = (float*)d_out;

    fused_modconv_kernel<<<dim3(HW / 1024, B_), 256, 0, stream>>>(
        x, w, weight, bias, affine_w, affine_b, out);
}

// Round 5
// 92.519 us; speedup vs baseline: 1.2418x; 1.2418x over previous
//
#include <hip/hip_runtime.h>
#include <hip/hip_bf16.h>

// out[b,o,h,w] = clip( sum_c x[b,c,h,w] * w2d[o,c] * styles[b,c] + bias[o], -256, 256 )
// styles[b,c] = (dot(w[b,:], affine_w[c,:]) / sqrt(512) + affine_b[c]) / sqrt(256)
// B=8, C_in=256, H=W=256, C_out=3, w_dim=512.  All fp32.
//
// Two-kernel structure (R3, 92.75 us): the styles GEMV is computed ONCE into
// d_ws (4 MB of affine_w traffic total), then the streaming kernel runs at
// ~98% of the measured 6.29 TB/s copy ceiling. Fusing the GEMV into the
// streaming kernel (R4) redid it per-block -> 256 MB L2 burst + serial
// prologue = +22 us. Keep them split.

#define B_    8
#define CIN   256
#define HW    65536          // 256*256
#define HW4   16384          // HW/4
#define COUT  3
#define WDIM  512

typedef float f4 __attribute__((ext_vector_type(4)));

// One wave per (b,c): dot(w[b,:512], affine_w[c,:512]) via shfl reduce.
// Output: mod[b*256+c] = {w2d[0,c]*s, w2d[1,c]*s, w2d[2,c]*s, 0}
__global__ __launch_bounds__(256) void mod_kernel(
    const float* __restrict__ w,          // (B, 512)
    const float* __restrict__ affine_w,   // (256, 512)
    const float* __restrict__ affine_b,   // (256,)
    const float* __restrict__ weight,     // (3, 256)
    f4* __restrict__ mod)                 // (B*256,) out
{
    const int wid  = threadIdx.x >> 6;          // wave 0..3
    const int lane = threadIdx.x & 63;
    const int idx  = blockIdx.x * 4 + wid;      // 0..2047
    const int b    = idx >> 8;
    const int c    = idx & 255;

    const f4* aw = (const f4*)(affine_w + (size_t)c * WDIM) + lane * 2;
    const f4* wv = (const f4*)(w + (size_t)b * WDIM) + lane * 2;
    f4 a0 = aw[0], a1 = aw[1];
    f4 q0 = wv[0], q1 = wv[1];
    float acc = a0.x * q0.x + a0.y * q0.y + a0.z * q0.z + a0.w * q0.w
              + a1.x * q1.x + a1.y * q1.y + a1.z * q1.z + a1.w * q1.w;
#pragma unroll
    for (int off = 32; off >= 1; off >>= 1)
        acc += __shfl_xor(acc, off, 64);

    if (lane == 0) {
        const float rs512 = 0.044194173824159216f;  // 1/sqrt(512)
        const float rs256 = 0.0625f;                // 1/sqrt(256)
        float s = (acc * rs512 + affine_b[c]) * rs256;
        f4 m;
        m.x = weight[0 * CIN + c] * s;
        m.y = weight[1 * CIN + c] * s;
        m.z = weight[2 * CIN + c] * s;
        m.w = 0.f;
        mod[idx] = m;
    }
}

__global__ __launch_bounds__(256) void modconv_kernel(
    const float* __restrict__ x,        // (B, 256, 256, 256)
    const f4* __restrict__ mod,         // (B*256,) premodulated weights
    const float* __restrict__ bias,     // (3,)
    float* __restrict__ out)            // (B, 3, 256, 256)
{
    const int b    = blockIdx.y;
    const int tile = blockIdx.x;        // 64 tiles of 1024 floats each
    const int tid  = threadIdx.x;       // 256

    __shared__ f4 ms[CIN];
    ms[tid] = mod[b * CIN + tid];
    __syncthreads();

    const f4* xp = (const f4*)x + (size_t)b * CIN * HW4 + (size_t)tile * 256 + tid;

    const float b0 = bias[0], b1 = bias[1], b2 = bias[2];
    f4 a0 = {b0, b0, b0, b0};
    f4 a1 = {b1, b1, b1, b1};
    f4 a2 = {b2, b2, b2, b2};

#pragma unroll 16
    for (int c = 0; c < CIN; ++c) {
        f4 xv = __builtin_nontemporal_load(xp + (size_t)c * HW4);
        f4 m  = ms[c];
        a0.x = fmaf(xv.x, m.x, a0.x);
        a0.y = fmaf(xv.y, m.x, a0.y);
        a0.z = fmaf(xv.z, m.x, a0.z);
        a0.w = fmaf(xv.w, m.x, a0.w);
        a1.x = fmaf(xv.x, m.y, a1.x);
        a1.y = fmaf(xv.y, m.y, a1.y);
        a1.z = fmaf(xv.z, m.y, a1.z);
        a1.w = fmaf(xv.w, m.y, a1.w);
        a2.x = fmaf(xv.x, m.z, a2.x);
        a2.y = fmaf(xv.y, m.z, a2.y);
        a2.z = fmaf(xv.z, m.z, a2.z);
        a2.w = fmaf(xv.w, m.z, a2.w);
    }

    const float CL = 256.0f;
    a0.x = fminf(fmaxf(a0.x, -CL), CL);
    a0.y = fminf(fmaxf(a0.y, -CL), CL);
    a0.z = fminf(fmaxf(a0.z, -CL), CL);
    a0.w = fminf(fmaxf(a0.w, -CL), CL);
    a1.x = fminf(fmaxf(a1.x, -CL), CL);
    a1.y = fminf(fmaxf(a1.y, -CL), CL);
    a1.z = fminf(fmaxf(a1.z, -CL), CL);
    a1.w = fminf(fmaxf(a1.w, -CL), CL);
    a2.x = fminf(fmaxf(a2.x, -CL), CL);
    a2.y = fminf(fmaxf(a2.y, -CL), CL);
    a2.z = fminf(fmaxf(a2.z, -CL), CL);
    a2.w = fminf(fmaxf(a2.w, -CL), CL);

    f4* op = (f4*)out + (size_t)b * COUT * HW4 + (size_t)tile * 256 + tid;
    __builtin_nontemporal_store(a0, op + 0 * HW4);
    __builtin_nontemporal_store(a1, op + 1 * HW4);
    __builtin_nontemporal_store(a2, op + 2 * HW4);
}

extern "C" void kernel_launch(void* const* d_in, const int* in_sizes, int n_in,
                              void* d_out, int out_size, void* d_ws, size_t ws_size,
                              hipStream_t stream) {
    const float* x        = (const float*)d_in[0];
    const float* w        = (const float*)d_in[1];
    const float* weight   = (const float*)d_in[2];
    const float* bias     = (const float*)d_in[3];
    const float* affine_w = (const float*)d_in[4];
    const float* affine_b = (const float*)d_in[5];
    float* out = (float*)d_out;
    f4* mod    = (f4*)d_ws;   // 2048 f4 = 32 KiB

    mod_kernel<<<dim3(B_ * CIN / 4), 256, 0, stream>>>(w, affine_w, affine_b, weight, mod);
    modconv_kernel<<<dim3(HW / 1024, B_), 256, 0, stream>>>(x, mod, bias, out);
}